// Round 10
// baseline (2906.549 us; speedup 1.0000x reference)
//
#include <hip/hip_runtime.h>
#include <math.h>

// ClusterNet round-10: round-9 with the butterfly-select bug FIXED.
//  Bug was: xor-4 finalize summed DIFFERENT k's across the lane pair
//  (lane o selected dp[2o], partner dp[2(o^4)]). Fix: pair-uniform quad
//  select dp[4(o&3)..+3], butterfly xor-4 on those, lane keeps 2 by o>>2:
//  k = 4(o&3)+2(o>>2) (+1). All k-indexed writes use ko.
//  BLK=512, TILE=64, 2 blocks/CU -> 16 waves/CU (4/SIMD).
//  Staging: global_load_lds w16, source-col XOR swizzle, vmcnt(4) counted.

#define N_ROWS 500000
#define D 128
#define K 16
#define TEMP 0.5f
#define EPSV 1e-8f
#define TILE 64
#define BLK 512
#define RL 18
#define NITER 11
#define NTILES ((N_ROWS + TILE - 1) / TILE)   // 7813
#define NB 512

typedef const __attribute__((address_space(1))) float4* gas_f4;
typedef __attribute__((address_space(3))) float4* las_f4;

__device__ __forceinline__ void gl_lds16(const float4* g, float4* l) {
    __builtin_amdgcn_global_load_lds((gas_f4)g, (las_f4)l, 16, 0, 0);
}

__global__ void k_init(const float* __restrict__ mu0,
                       float* __restrict__ mn,
                       float* __restrict__ accum) {
    __shared__ float m1[K * D];
    __shared__ float inv[K];
    const int t = threadIdx.x;
    for (int i = t; i < K * D + K; i += 256) accum[i] = 0.0f;
    if (t < K) {
        float ss = 0.0f;
        for (int d = 0; d < D; ++d) { float v = mu0[t * D + d]; ss += v * v; }
        inv[t] = 1.0f / sqrtf(ss);
    }
    __syncthreads();
    for (int i = t; i < K * D; i += 256) m1[i] = mu0[i] * inv[i / D];
    __syncthreads();
    if (t < K) {
        float ss = 0.0f;
        for (int d = 0; d < D; ++d) { float v = m1[t * D + d]; ss += v * v; }
        inv[t] = 1.0f / sqrtf(ss);
    }
    __syncthreads();
    for (int i = t; i < K * D; i += 256) mn[i] = m1[i] * inv[i / D];
}

__global__ __launch_bounds__(BLK) void k_main(const float* __restrict__ e,
                                              const float* __restrict__ mn,
                                              float* __restrict__ accum,
                                              float* __restrict__ r_out,
                                              int write_r) {
    __shared__ float4 elds[2][TILE * 32];   // 2 x 32 KB e tiles (swizzled cols)
    __shared__ float4 mn_lds4[K * 32];      // 8 KB unit centroids
    __shared__ float  rlds[TILE * RL];      // 4.5 KB r~ rows (reused for cr)

    const int t  = threadIdx.x;
    const int wv = t >> 6;        // wave 0..7
    const int ln = t & 63;
    const int g  = t >> 3;        // A: row 0..63
    const int o  = t & 7;         // A: octant
    const int d4 = t & 31;        // B: float4 column
    const int kp = (t >> 5) & 7;  // B: k-pair
    const int ph = t >> 8;        // B: p-half 0..1

    const float4* __restrict__ e4 = (const float4*)e;

    int tile = blockIdx.x;
    // ---- prologue: tile0 prefetch (async) + mn stage ----
    #pragma unroll
    for (int i = 0; i < 4; ++i) {
        const int sigma = wv * 256 + i * 64 + ln;
        const int sg = sigma >> 5, s = sigma & 31;
        int row = tile * TILE + sg; if (row > N_ROWS - 1) row = N_ROWS - 1;
        gl_lds16(e4 + row * 32 + (s ^ (sg & 31)), &elds[0][sigma]);
    }
    mn_lds4[t] = ((const float4*)mn)[t & 511];   // t<512; only first 512 slots
    asm volatile("s_waitcnt lgkmcnt(0)" ::: "memory");
    __builtin_amdgcn_sched_barrier(0);
    __builtin_amdgcn_s_barrier();           // mn ready (tile0 still in flight)
    __builtin_amdgcn_sched_barrier(0);

    float acc0[4] = {0.f,0.f,0.f,0.f};
    float acc1[4] = {0.f,0.f,0.f,0.f};
    float cr0 = 0.f, cr1 = 0.f;

    int buf = 0;
    for (; tile < NTILES; tile += NB, buf ^= 1) {
        const int base = tile * TILE;
        const int nt = tile + NB;
        if (nt < NTILES) {                   // async prefetch next tile
            #pragma unroll
            for (int i = 0; i < 4; ++i) {
                const int sigma = wv * 256 + i * 64 + ln;
                const int sg = sigma >> 5, s = sigma & 31;
                int row = nt * TILE + sg; if (row > N_ROWS - 1) row = N_ROWS - 1;
                gl_lds16(e4 + row * 32 + (s ^ (sg & 31)), &elds[buf ^ 1][sigma]);
            }
            asm volatile("s_waitcnt vmcnt(4)" ::: "memory");   // cur tile landed
        } else {
            asm volatile("s_waitcnt vmcnt(0)" ::: "memory");
        }
        __builtin_amdgcn_sched_barrier(0);
        __builtin_amdgcn_s_barrier();        // cur elds ready
        __builtin_amdgcn_sched_barrier(0);

        const float4* __restrict__ eb = (const float4*)elds[buf];
        const int row = base + g;
        const bool valid = row < N_ROWS;

        // ---- phase A: partial dots over this lane's 16 dims ----
        float dp[16];
        #pragma unroll
        for (int k = 0; k < 16; ++k) dp[k] = 0.0f;
        float ss = 0.0f;
        #pragma unroll
        for (int c = 0; c < 4; ++c) {
            const float4 ev = eb[(g << 5) + (((c << 3) + o) ^ (g & 31))];
            ss += ev.x * ev.x + ev.y * ev.y + ev.z * ev.z + ev.w * ev.w;
            #pragma unroll
            for (int k = 0; k < 16; ++k) {
                const float4 m = mn_lds4[k * 32 + (c << 3) + o];
                dp[k] += ev.x * m.x + ev.y * m.y + ev.z * m.z + ev.w * m.w;
            }
        }
        // butterfly xor1,2 (within xor-4 half), all 16 k
        #pragma unroll
        for (int k = 0; k < 16; ++k) {
            dp[k] += __shfl_xor(dp[k], 1);
            dp[k] += __shfl_xor(dp[k], 2);
        }
        ss += __shfl_xor(ss, 1);
        ss += __shfl_xor(ss, 2);
        ss += __shfl_xor(ss, 4);

        // PAIR-UNIFORM quad select (o&3 identical across the xor-4 pair),
        // butterfly xor-4 on the quad -> full dots; lane keeps 2 by o>>2.
        float q0 = dp[0], q1 = dp[1], q2 = dp[2], q3 = dp[3];
        #pragma unroll
        for (int mm = 1; mm < 4; ++mm) {
            if ((o & 3) == mm) {
                q0 = dp[4 * mm];     q1 = dp[4 * mm + 1];
                q2 = dp[4 * mm + 2]; q3 = dp[4 * mm + 3];
            }
        }
        q0 += __shfl_xor(q0, 4);
        q1 += __shfl_xor(q1, 4);
        q2 += __shfl_xor(q2, 4);
        q3 += __shfl_xor(q3, 4);
        const int hi = o >> 2;
        const float s0 = hi ? q2 : q0;
        const float s1 = hi ? q3 : q1;
        const int ko = 4 * (o & 3) + 2 * hi;   // this lane's ks: ko, ko+1

        const float nrm  = sqrtf(ss);
        const float binv = 1.0f / nrm;            // dn scale (no eps)
        const float ainv = 1.0f / (nrm + EPSV);   // data scale (with eps)

        const float dd0 = -TEMP * binv * s0;
        const float dd1 = -TEMP * binv * s1;
        float mx = fmaxf(dd0, dd1);
        mx = fmaxf(mx, __shfl_xor(mx, 1));
        mx = fmaxf(mx, __shfl_xor(mx, 2));
        mx = fmaxf(mx, __shfl_xor(mx, 4));
        const float e0 = __expf(dd0 - mx);
        const float e1 = __expf(dd1 - mx);
        float sm = e0 + e1;
        sm += __shfl_xor(sm, 1);
        sm += __shfl_xor(sm, 2);
        sm += __shfl_xor(sm, 4);
        const float isum = 1.0f / sm;
        const float r0 = valid ? e0 * isum : 0.0f;
        const float r1 = valid ? e1 * isum : 0.0f;
        cr0 += r0; cr1 += r1;

        *(float2*)&rlds[g * RL + ko] = make_float2(r0 * ainv, r1 * ainv);
        if (write_r && valid)
            *(float2*)(r_out + row * K + ko) = make_float2(r0, r1);

        asm volatile("s_waitcnt lgkmcnt(0)" ::: "memory");
        __builtin_amdgcn_sched_barrier(0);
        __builtin_amdgcn_s_barrier();        // r~ visible
        __builtin_amdgcn_sched_barrier(0);

        // ---- phase B: acc[k][d] += r~[p] * e[p][d] (all from LDS) ----
        #pragma unroll 8
        for (int i = 0; i < 32; ++i) {
            const int p = (ph << 5) + i;
            const float4 ev = eb[(p << 5) + (d4 ^ i)];
            const float2 rr = *(const float2*)&rlds[p * RL + (kp << 1)];
            acc0[0] += rr.x * ev.x; acc0[1] += rr.x * ev.y;
            acc0[2] += rr.x * ev.z; acc0[3] += rr.x * ev.w;
            acc1[0] += rr.y * ev.x; acc1[1] += rr.y * ev.y;
            acc1[2] += rr.y * ev.z; acc1[3] += rr.y * ev.w;
        }
        __builtin_amdgcn_sched_barrier(0);
        __builtin_amdgcn_s_barrier();        // elds/rlds consumption done
        __builtin_amdgcn_sched_barrier(0);
    }

    // ---- merge cluster_mean: (kp, d4) cells, ph halves via atomics ----
    #pragma unroll
    for (int j = 0; j < 4; ++j)
        atomicAdd(&accum[(2 * kp) * D + d4 * 4 + j], acc0[j]);
    #pragma unroll
    for (int j = 0; j < 4; ++j)
        atomicAdd(&accum[(2 * kp + 1) * D + d4 * 4 + j], acc1[j]);

    // ---- block-reduce cluster_r (cr holds ks ko,ko+1 of row g) ----
    __syncthreads();
    {
        const int o2 = t & 7;
        const int ko2 = 4 * (o2 & 3) + 2 * (o2 >> 2);
        float* fld = (float*)rlds;           // 1024 floats used (fits 1152)
        *(float2*)&fld[((t >> 3) << 4) + ko2] = make_float2(cr0, cr1);
    }
    __syncthreads();
    if (t < K) {
        float* fld = (float*)rlds;
        float s = 0.0f;
        #pragma unroll 8
        for (int gg = 0; gg < 64; ++gg) s += fld[gg * 16 + t];
        atomicAdd(&accum[K * D + t], s);
    }
}

__global__ void k_update(float* __restrict__ accum,
                         float* __restrict__ mn,
                         float* __restrict__ mu_out,
                         int last) {
    __shared__ float mu[K * D];
    __shared__ float inv[K];
    const int t = threadIdx.x;
    for (int i = t; i < K * D; i += 256)
        mu[i] = accum[i] / accum[K * D + i / D];
    __syncthreads();
    if (last) {
        for (int i = t; i < K * D; i += 256) mu_out[i] = mu[i];
    } else {
        if (t < K) {
            float ssq = 0.0f;
            for (int d = 0; d < D; ++d) { float v = mu[t * D + d]; ssq += v * v; }
            inv[t] = 1.0f / sqrtf(ssq);
        }
        __syncthreads();
        for (int i = t; i < K * D; i += 256) mu[i] *= inv[i / D];
        __syncthreads();
        if (t < K) {
            float ssq = 0.0f;
            for (int d = 0; d < D; ++d) { float v = mu[t * D + d]; ssq += v * v; }
            inv[t] = 1.0f / sqrtf(ssq);
        }
        __syncthreads();
        for (int i = t; i < K * D; i += 256) mn[i] = mu[i] * inv[i / D];
    }
    __syncthreads();
    for (int i = t; i < K * D + K; i += 256) accum[i] = 0.0f;
}

extern "C" void kernel_launch(void* const* d_in, const int* in_sizes, int n_in,
                              void* d_out, int out_size, void* d_ws, size_t ws_size,
                              hipStream_t stream) {
    const float* e   = (const float*)d_in[0];   // [N, D] f32
    const float* mu0 = (const float*)d_in[1];   // [K, D] f32
    float* out = (float*)d_out;                 // mu [K*D] then r [N*K]
    float* ws  = (float*)d_ws;

    float* mn    = ws;            // [K*D]
    float* accum = ws + K * D;    // [K*D + K]
    float* r_out = out + K * D;

    hipLaunchKernelGGL(k_init, dim3(1), dim3(256), 0, stream, mu0, mn, accum);
    for (int it = 0; it < NITER; ++it) {
        const int last = (it == NITER - 1) ? 1 : 0;
        hipLaunchKernelGGL(k_main, dim3(NB), dim3(BLK), 0, stream,
                           e, mn, accum, r_out, last);
        hipLaunchKernelGGL(k_update, dim3(1), dim3(256), 0, stream,
                           accum, mn, out, last);
    }
}